// Round 17
// baseline (76.281 us; speedup 1.0000x reference)
//
#include <hip/hip_runtime.h>
#include <hip/hip_bf16.h>

#define NN 30000
#define DIM 128
#define NT 6
#define NE 480000
#define NSLOT 1024
#define NSEG (NT*3*NSLOT)   // 18432
#define SEGCAP 96
#define NBM ((NN+31)/32)    // 938
#define QCAP 2048
#define HB 2048
#define NBUILD 2124         // 118*18
#define NCAST 876
#define NAGG (NSEG/16)      // 1152

typedef __attribute__((ext_vector_type(8))) short bf16x8;
typedef __attribute__((ext_vector_type(4))) float f32x4;

__device__ __forceinline__ float lrelu(float x){ return x > 0.f ? x : 0.2f*x; }
__device__ __forceinline__ unsigned short f2b(float f){
    unsigned u = __float_as_uint(f);
    u = (u + 0x7FFFu + ((u>>16)&1u)) >> 16;
    return (unsigned short)u;
}
__device__ __forceinline__ float b2f(unsigned short b){
    return __uint_as_float(((unsigned)b)<<16);
}
__device__ __forceinline__ float blo(unsigned p){ return b2f((unsigned short)(p & 0xFFFF)); }
__device__ __forceinline__ float bhi(unsigned p){ return b2f((unsigned short)(p >> 16)); }
__device__ __forceinline__ unsigned hsh(int v){ return ((unsigned)v*2654435761u >> 21) & (HB-1); }

// blocks 0..3: WT transpose (+wa for 0,1); block 4: hash/bitmap/rep; blocks 5..12: zero cnt
__global__ void k_prep(const float* __restrict__ Wp, const float* __restrict__ Wc,
        const float* __restrict__ Wl, const float* __restrict__ Wr,
        const float* __restrict__ aspv, const float* __restrict__ adpv,
        const float* __restrict__ ascv, const float* __restrict__ adcv,
        const int* __restrict__ s, unsigned* __restrict__ bm,
        unsigned* __restrict__ hmap, int* __restrict__ rep, int* __restrict__ cnt,
        float* __restrict__ wa, unsigned short* __restrict__ WT4){
    int m = blockIdx.x, t = threadIdx.x;
    if (m >= 5){
        int b = m - 5;
        int per = (NSEG + 7)/8;
        for (int j = b*per + t; j < (b+1)*per && j < NSEG; j += 256) cnt[j] = 0;
        return;
    }
    if (m == 4){
        __shared__ int hk[HB];
        __shared__ int hv[HB];
        __shared__ unsigned bms[NBM];
        for (int j = t; j < HB; j += 256){ hk[j] = -1; hv[j] = 1<<30; }
        for (int j = t; j < NBM; j += 256) bms[j] = 0u;
        __syncthreads();
        for (int i = t; i < NSLOT; i += 256){
            int v = s[i];
            unsigned idx = hsh(v);
            while (true){
                int old = atomicCAS(&hk[idx], -1, v);
                if (old == -1 || old == v){ atomicMin(&hv[idx], i); break; }
                idx = (idx+1)&(HB-1);
            }
            atomicOr(&bms[v>>5], 1u << (v&31));
        }
        __syncthreads();
        for (int j = t; j < NBM; j += 256) bm[j] = bms[j];
        for (int j = t; j < HB; j += 256){
            int k = hk[j];
            hmap[j] = (k < 0) ? 0xFFFFFFFFu : (((unsigned)k << 10) | (unsigned)hv[j]);
        }
        for (int i = t; i < NSLOT; i += 256){
            int v = s[i];
            unsigned idx = hsh(v);
            while (hk[idx] != v) idx = (idx+1)&(HB-1);
            rep[i] = hv[idx];
        }
        return;
    }
    const float* W = (m==0) ? Wp : (m==1) ? Wc : (m==2) ? Wl : Wr;
    unsigned short* WT = WT4 + (size_t)m*DIM*DIM;
    if (m < 2 && t < DIM){
        const float* avs = m ? ascv : aspv;
        const float* avd = m ? adcv : adpv;
        float* wab = wa + m*2*DIM;
        float sv = 0.f, dv = 0.f;
        for (int n = 0; n < DIM; n++){
            float w = W[t*DIM + n];
            sv += w*avs[n]; dv += w*avd[n];
        }
        wab[t] = sv; wab[DIM + t] = dv;
    }
    for (int j = t; j < DIM*DIM; j += blockDim.x){
        int n = j >> 7, k = j & 127;
        WT[n*DIM + k] = f2b(W[k*DIM + n]);
    }
}

// blocks [0,NCAST): cast (grid-stride, wave/node); [NCAST, NCAST+NBUILD): CSR build
__global__ __launch_bounds__(256) void k_castbuild(
        const float* __restrict__ X, const float* __restrict__ wa,
        unsigned* __restrict__ Xbf,
        float* __restrict__ asp, float* __restrict__ adp,
        float* __restrict__ asc, float* __restrict__ adc,
        const int* __restrict__ EI,
        const unsigned* __restrict__ bm, const unsigned* __restrict__ hmap,
        int* __restrict__ cnt, int* __restrict__ csr){
    __shared__ unsigned bms[NBM];
    __shared__ unsigned q[QCAP];
    __shared__ int qn;
    int bx = blockIdx.x;
    int lane = threadIdx.x & 63;
    int wib = threadIdx.x >> 6;
    if (bx < NCAST){
        for (int node = bx*4 + wib; node < NN; node += NCAST*4){
            float2 x = *(const float2*)&X[(size_t)node*DIM + lane*2];
            Xbf[(size_t)node*64 + lane] = (unsigned)f2b(x.x) | ((unsigned)f2b(x.y) << 16);
            float sp = x.x*wa[2*lane]     + x.y*wa[2*lane+1];
            float dp = x.x*wa[128+2*lane] + x.y*wa[128+2*lane+1];
            float sc = x.x*wa[256+2*lane] + x.y*wa[256+2*lane+1];
            float dc = x.x*wa[384+2*lane] + x.y*wa[384+2*lane+1];
            #pragma unroll
            for (int off = 32; off; off >>= 1){
                sp += __shfl_xor(sp, off); dp += __shfl_xor(dp, off);
                sc += __shfl_xor(sc, off); dc += __shfl_xor(dc, off);
            }
            if (lane == 0){ asp[node]=sp; adp[node]=dp; asc[node]=sc; adc[node]=dc; }
        }
        return;
    }
    int bb = bx - NCAST;
    int row = bb / 118, bxx = bb - row*118;
    for (int j = threadIdx.x; j < NBM; j += 256) bms[j] = bm[j];
    if (threadIdx.x == 0) qn = 0;
    __syncthreads();
    const int Q = NE/4;
    const int G = 118*256;
    const int4* dstp = (const int4*)(EI + (size_t)(2*row+1)*NE);
    const int4* srcp = (const int4*)(EI + (size_t)(2*row)*NE);
    int tid = bxx*256 + threadIdx.x;

    int4 d[4]; int ix[4]; bool va[4];
    #pragma unroll
    for (int u = 0; u < 4; u++){
        ix[u] = tid + u*G;
        va[u] = ix[u] < Q;
        d[u] = va[u] ? dstp[ix[u]] : make_int4(0,0,0,0);
    }
    unsigned mk[4];
    #pragma unroll
    for (int u = 0; u < 4; u++){
        unsigned m0 = va[u] ? ((bms[d[u].x>>5] >> (d[u].x&31)) & 1u) : 0u;
        unsigned m1 = va[u] ? ((bms[d[u].y>>5] >> (d[u].y&31)) & 1u) : 0u;
        unsigned m2 = va[u] ? ((bms[d[u].z>>5] >> (d[u].z&31)) & 1u) : 0u;
        unsigned m3 = va[u] ? ((bms[d[u].w>>5] >> (d[u].w&31)) & 1u) : 0u;
        mk[u] = m0 | (m1<<1) | (m2<<2) | (m3<<3);
    }
    int4 sv[4];
    #pragma unroll
    for (int u = 0; u < 4; u++)
        if (mk[u]) sv[u] = srcp[ix[u]];
    #pragma unroll
    for (int u = 0; u < 4; u++){
        #pragma unroll
        for (int c = 0; c < 4; c++){
            bool p = (mk[u] >> c) & 1u;
            unsigned long long bal = __ballot(p);
            if (bal){
                int cntw = __popcll(bal);
                int base = 0;
                if (lane == 0) base = atomicAdd(&qn, cntw);
                base = __shfl(base, 0);
                if (p){
                    int dv = (c==0)?d[u].x:(c==1)?d[u].y:(c==2)?d[u].z:d[u].w;
                    int so = (c==0)?sv[u].x:(c==1)?sv[u].y:(c==2)?sv[u].z:sv[u].w;
                    int pos = base + __popcll(bal & ((1ull<<lane)-1ull));
                    if (pos < QCAP) q[pos] = ((unsigned)dv<<15) | (unsigned)so;
                }
            }
        }
    }
    __syncthreads();
    int base = row*NSLOT;
    int tot = qn; if (tot > QCAP) tot = QCAP;
    for (int j = threadIdx.x; j < tot; j += 256){
        unsigned e = q[j];
        int dst = (int)(e >> 15);
        int src = (int)(e & 32767u);
        unsigned idx = hsh(dst);
        unsigned he;
        while (((he = hmap[idx]) >> 10) != (unsigned)dst) idx = (idx+1)&(HB-1);
        int sl = (int)(he & 1023u);
        int p = atomicAdd(&cnt[base+sl], 1);
        if (p < SEGCAP) csr[(size_t)(base+sl)*SEGCAP + p] = src;
    }
}

// blocks [0,NAGG): 16 segments/block, 8 waves x 2 segments -> LDS -> MFMA -> aggOut
// blocks [NAGG, NAGG+8): Xbf[s]@WrT -> xWr (128 rows/block)
__global__ __launch_bounds__(512) void k_aggemm(const unsigned* __restrict__ Xbf,
        const float* __restrict__ asp, const float* __restrict__ adp,
        const float* __restrict__ asc, const float* __restrict__ adc,
        const int* __restrict__ s, const int* __restrict__ cnt, const int* __restrict__ csr,
        const unsigned short* __restrict__ WT4,
        float* __restrict__ aggOut, float* __restrict__ xWr){
    __shared__ unsigned tile[16][72];   // 288B row: 16B-aligned, low-conflict
    int bx = blockIdx.x;
    int lane = threadIdx.x & 63;
    int wib = threadIdx.x >> 6;         // 0..7
    if (bx >= NAGG){
        int blk = bx - NAGG;
        const unsigned short* WT = WT4 + (size_t)3*DIM*DIM;
        int r0 = blk*128 + wib*16;
        int ar = r0 + (lane & 15); if (ar > NSLOT-1) ar = NSLOT-1;
        int g4 = lane >> 4;
        const unsigned short* Arow = (const unsigned short*)(Xbf + (size_t)s[ar]*64);
        bf16x8 Af[4];
        #pragma unroll
        for (int ks = 0; ks < 4; ks++)
            Af[ks] = *(const bf16x8*)&Arow[ks*32 + g4*8];
        int cl = lane & 15;
        #pragma unroll
        for (int ct = 0; ct < 8; ct++){
            f32x4 acc = {0.f,0.f,0.f,0.f};
            int bcol = ct*16 + cl;
            #pragma unroll
            for (int ks = 0; ks < 4; ks++){
                bf16x8 bF = *(const bf16x8*)&WT[bcol*DIM + ks*32 + g4*8];
                acc = __builtin_amdgcn_mfma_f32_16x16x32_bf16(Af[ks], bF, acc, 0, 0, 0);
            }
            #pragma unroll
            for (int r = 0; r < 4; r++){
                int rw = r0 + g4*4 + r;
                if (rw < NSLOT) xWr[(size_t)rw*DIM + bcol] = acc[r];
            }
        }
        return;
    }
    int base_gw = bx*16;
    int tg = base_gw >> 10;
    int g = tg % 3;
    const float* as = (g==1) ? asc : asp;
    const float* ad = (g==1) ? adc : adp;

    // ---- hoisted segment heads: 2 segments per wave, all loads independent ----
    int nA[2], s0A[2], s1A[2];
    #pragma unroll
    for (int k = 0; k < 2; k++)
        nA[k] = cnt[base_gw + wib*2 + k];
    #pragma unroll
    for (int k = 0; k < 2; k++){
        const int* lst = csr + (size_t)(base_gw + wib*2 + k)*SEGCAP;
        s0A[k] = lst[lane];
        s1A[k] = (lane < 32) ? lst[64+lane] : 0;   // entries >=96 never used
    }
    #pragma unroll
    for (int k = 0; k < 2; k++){
        if (nA[k] > SEGCAP) nA[k] = SEGCAP;
        if (lane >= nA[k]) s0A[k] = 0;
        if (64+lane >= nA[k]) s1A[k] = 0;
    }
    float w0A[2], w1A[2], wsA[2], scA[2];
    unsigned pkvA[2];
    int vA[2];
    if (g < 2){
        #pragma unroll
        for (int k = 0; k < 2; k++)
            vA[k] = s[(base_gw + wib*2 + k) & (NSLOT-1)];
        float advA[2], easA[2];
        #pragma unroll
        for (int k = 0; k < 2; k++){ advA[k] = ad[vA[k]]; easA[k] = as[vA[k]]; }
        float e0A[2], e1A[2];
        #pragma unroll
        for (int k = 0; k < 2; k++){
            e0A[k] = as[s0A[k]];
            e1A[k] = as[s1A[k]];
        }
        #pragma unroll
        for (int k = 0; k < 2; k++)
            pkvA[k] = Xbf[(size_t)vA[k]*64 + lane];
        #pragma unroll
        for (int k = 0; k < 2; k++){
            float eself = lrelu(easA[k] + advA[k]);
            float e0 = (lane < nA[k])    ? lrelu(e0A[k] + advA[k]) : -3e38f;
            float e1 = (64+lane < nA[k]) ? lrelu(e1A[k] + advA[k]) : -3e38f;
            float m = fmaxf(eself, fmaxf(e0, e1));
            #pragma unroll
            for (int off = 32; off; off >>= 1) m = fmaxf(m, __shfl_xor(m, off));
            float w0 = (lane < nA[k])    ? __expf(e0 - m) : 0.f;
            float w1 = (64+lane < nA[k]) ? __expf(e1 - m) : 0.f;
            float ds = w0 + w1;
            #pragma unroll
            for (int off = 32; off; off >>= 1) ds += __shfl_xor(ds, off);
            float wself = __expf(eself - m);
            w0A[k] = w0; w1A[k] = w1; wsA[k] = wself;
            scA[k] = 1.f / (wself + ds);
        }
    } else {
        #pragma unroll
        for (int k = 0; k < 2; k++){
            w0A[k] = (lane < nA[k]) ? 1.f : 0.f;
            w1A[k] = (64+lane < nA[k]) ? 1.f : 0.f;
            wsA[k] = 0.f;
            scA[k] = 1.f / (float)(nA[k] > 0 ? nA[k] : 1);
        }
    }

    // ---- gather-accumulate per segment ----
    #pragma unroll
    for (int k = 0; k < 2; k++){
        int n = nA[k];
        int n0 = n < 64 ? n : 64;
        int src0 = s0A[k], src1 = s1A[k];
        float w0 = w0A[k], w1 = w1A[k];
        float a0 = 0.f, a1 = 0.f;
        int j = 0;
        for (; j+7 < n0; j += 8){
            int   si[8]; float qi[8]; unsigned ki[8];
            #pragma unroll
            for (int u = 0; u < 8; u++){ si[u] = __shfl(src0, j+u); qi[u] = __shfl(w0, j+u); }
            #pragma unroll
            for (int u = 0; u < 8; u++) ki[u] = Xbf[(size_t)si[u]*64 + lane];
            #pragma unroll
            for (int u = 0; u < 8; u++){ a0 += qi[u]*blo(ki[u]); a1 += qi[u]*bhi(ki[u]); }
        }
        for (; j+3 < n0; j += 4){
            int s0=__shfl(src0,j), s1=__shfl(src0,j+1), s2=__shfl(src0,j+2), s3=__shfl(src0,j+3);
            float q0=__shfl(w0,j), q1=__shfl(w0,j+1), q2=__shfl(w0,j+2), q3=__shfl(w0,j+3);
            unsigned k0=Xbf[(size_t)s0*64+lane];
            unsigned k1=Xbf[(size_t)s1*64+lane];
            unsigned k2=Xbf[(size_t)s2*64+lane];
            unsigned k3=Xbf[(size_t)s3*64+lane];
            a0 += q0*blo(k0) + q1*blo(k1) + q2*blo(k2) + q3*blo(k3);
            a1 += q0*bhi(k0) + q1*bhi(k1) + q2*bhi(k2) + q3*bhi(k3);
        }
        for (; j < n0; j++){
            int sj=__shfl(src0,j);
            float qj=__shfl(w0,j);
            unsigned pk=Xbf[(size_t)sj*64+lane];
            a0 += qj*blo(pk); a1 += qj*bhi(pk);
        }
        for (j = 64; j < n; j++){
            int sj=__shfl(src1,j-64);
            float qj=__shfl(w1,j-64);
            unsigned pk=Xbf[(size_t)sj*64+lane];
            a0 += qj*blo(pk); a1 += qj*bhi(pk);
        }
        if (g < 2){
            a0 += wsA[k]*blo(pkvA[k]);
            a1 += wsA[k]*bhi(pkvA[k]);
        }
        tile[wib*2+k][lane] = (unsigned)f2b(a0*scA[k]) | ((unsigned)f2b(a1*scA[k]) << 16);
    }
    __syncthreads();
    // GEMM: 16 rows x 128 cols; wave wib does cols [wib*16, wib*16+16)
    const unsigned short* WT = WT4 + (size_t)g*DIM*DIM;
    int r = lane & 15, g4 = lane >> 4;
    bf16x8 Af[4];
    #pragma unroll
    for (int ks = 0; ks < 4; ks++)
        Af[ks] = *(const bf16x8*)&tile[r][ks*16 + g4*4];
    f32x4 acc = {0.f,0.f,0.f,0.f};
    int bcol = wib*16 + r;
    #pragma unroll
    for (int ks = 0; ks < 4; ks++){
        bf16x8 bF = *(const bf16x8*)&WT[bcol*DIM + ks*32 + g4*8];
        acc = __builtin_amdgcn_mfma_f32_16x16x32_bf16(Af[ks], bF, acc, 0, 0, 0);
    }
    #pragma unroll
    for (int rr = 0; rr < 4; rr++){
        int segrow = g4*4 + rr;
        aggOut[(size_t)(base_gw + segrow)*DIM + bcol] = acc[rr];
    }
}

__global__ void k_gather(const int* __restrict__ rep,
                         const float* __restrict__ aggOut, const float* __restrict__ xWr,
                         const float* __restrict__ bp, const float* __restrict__ bc,
                         const float* __restrict__ bl, const float* __restrict__ br,
                         float* __restrict__ out){
    int i = blockIdx.x*blockDim.x + threadIdx.x;
    if (i >= NT*NSLOT*DIM) return;
    int d = i & 127;
    int r = (i >> 7) & (NSLOT-1);
    int t = i >> 17;
    int rp = rep[r];
    size_t base = ((size_t)(t*3)*NSLOT + rp)*DIM + d;
    out[i] = (aggOut[base] + aggOut[base + NSLOT*DIM] + aggOut[base + 2*NSLOT*DIM]
              + xWr[(size_t)rp*DIM + d]
              + bp[d] + bc[d] + bl[d] + br[d]) * (1.f/3.f);
}

extern "C" void kernel_launch(void* const* d_in, const int* in_sizes, int n_in,
                              void* d_out, int out_size, void* d_ws, size_t ws_size,
                              hipStream_t stream) {
    const int*   s    = (const int*)d_in[0];
    const int*   EI   = (const int*)d_in[3];
    const float* X    = (const float*)d_in[4];
    const float* Wp   = (const float*)d_in[5];
    const float* aspv = (const float*)d_in[6];
    const float* adpv = (const float*)d_in[7];
    const float* bp   = (const float*)d_in[8];
    const float* Wc   = (const float*)d_in[9];
    const float* ascv = (const float*)d_in[10];
    const float* adcv = (const float*)d_in[11];
    const float* bc   = (const float*)d_in[12];
    const float* Wl   = (const float*)d_in[13];
    const float* bl   = (const float*)d_in[14];
    const float* Wr   = (const float*)d_in[15];
    const float* br   = (const float*)d_in[16];
    float* out = (float*)d_out;

    char* w = (char*)d_ws;
    unsigned* Xbf = (unsigned*)w; w += (size_t)NN*64*4;
    unsigned short* WT4 = (unsigned short*)w; w += (size_t)4*DIM*DIM*2;
    float* wa  = (float*)w; w += (size_t)4*DIM*4;
    float* asp = (float*)w; w += (size_t)NN*4;
    float* adp = (float*)w; w += (size_t)NN*4;
    float* asc = (float*)w; w += (size_t)NN*4;
    float* adc = (float*)w; w += (size_t)NN*4;
    unsigned* bm = (unsigned*)w; w += (size_t)((NBM+3)&~3)*4;
    unsigned* hmap = (unsigned*)w; w += (size_t)HB*4;
    int* rep  = (int*)w; w += (size_t)NSLOT*4;
    int* cnt  = (int*)w; w += (size_t)NSEG*4;
    int* csr  = (int*)w; w += (size_t)NSEG*SEGCAP*4;
    float* aggOut = (float*)w; w += (size_t)NSEG*DIM*4;
    float* xWr = (float*)w; w += (size_t)NSLOT*DIM*4;

    k_prep      <<<13, 256, 0, stream>>>(Wp, Wc, Wl, Wr, aspv, adpv, ascv, adcv,
                                         s, bm, hmap, rep, cnt, wa, WT4);
    k_castbuild <<<NCAST+NBUILD, 256, 0, stream>>>(X, wa, Xbf, asp, adp, asc, adc,
                                                   EI, bm, hmap, cnt, csr);
    k_aggemm    <<<NAGG+8, 512, 0, stream>>>(Xbf, asp, adp, asc, adc, s, cnt, csr,
                                             WT4, aggOut, xWr);
    k_gather    <<<NT*NSLOT*DIM/256, 256, 0, stream>>>(rep, aggOut, xWr, bp, bc, bl, br, out);
}

// Round 18
// 74.029 us; speedup vs baseline: 1.0304x; 1.0304x over previous
//
#include <hip/hip_runtime.h>
#include <hip/hip_bf16.h>

#define NN 30000
#define DIM 128
#define NT 6
#define NE 480000
#define NSLOT 1024
#define NSEG (NT*3*NSLOT)   // 18432
#define SEGCAP 96
#define NBM ((NN+31)/32)    // 938
#define QCAP 2048
#define HB 2048
#define NBUILD 2124         // 118*18
#define NCAST 876
#define NAGG (NSEG/16)      // 1152

typedef __attribute__((ext_vector_type(8))) short bf16x8;
typedef __attribute__((ext_vector_type(4))) float f32x4;

__device__ __forceinline__ float lrelu(float x){ return x > 0.f ? x : 0.2f*x; }
__device__ __forceinline__ unsigned short f2b(float f){
    unsigned u = __float_as_uint(f);
    u = (u + 0x7FFFu + ((u>>16)&1u)) >> 16;
    return (unsigned short)u;
}
__device__ __forceinline__ float b2f(unsigned short b){
    return __uint_as_float(((unsigned)b)<<16);
}
__device__ __forceinline__ float blo(unsigned p){ return b2f((unsigned short)(p & 0xFFFF)); }
__device__ __forceinline__ float bhi(unsigned p){ return b2f((unsigned short)(p >> 16)); }
__device__ __forceinline__ unsigned hsh(int v){ return ((unsigned)v*2654435761u >> 21) & (HB-1); }

// blocks 0..3: WT transpose (+wa for 0,1); block 4: hash/bitmap/rep; blocks 5..12: zero cnt
__global__ void k_prep(const float* __restrict__ Wp, const float* __restrict__ Wc,
        const float* __restrict__ Wl, const float* __restrict__ Wr,
        const float* __restrict__ aspv, const float* __restrict__ adpv,
        const float* __restrict__ ascv, const float* __restrict__ adcv,
        const int* __restrict__ s, unsigned* __restrict__ bm,
        unsigned* __restrict__ hmap, int* __restrict__ rep, int* __restrict__ cnt,
        float* __restrict__ wa, unsigned short* __restrict__ WT4){
    int m = blockIdx.x, t = threadIdx.x;
    if (m >= 5){
        int b = m - 5;
        int per = (NSEG + 7)/8;
        for (int j = b*per + t; j < (b+1)*per && j < NSEG; j += 256) cnt[j] = 0;
        return;
    }
    if (m == 4){
        __shared__ int hk[HB];
        __shared__ int hv[HB];
        __shared__ unsigned bms[NBM];
        for (int j = t; j < HB; j += 256){ hk[j] = -1; hv[j] = 1<<30; }
        for (int j = t; j < NBM; j += 256) bms[j] = 0u;
        __syncthreads();
        for (int i = t; i < NSLOT; i += 256){
            int v = s[i];
            unsigned idx = hsh(v);
            while (true){
                int old = atomicCAS(&hk[idx], -1, v);
                if (old == -1 || old == v){ atomicMin(&hv[idx], i); break; }
                idx = (idx+1)&(HB-1);
            }
            atomicOr(&bms[v>>5], 1u << (v&31));
        }
        __syncthreads();
        for (int j = t; j < NBM; j += 256) bm[j] = bms[j];
        for (int j = t; j < HB; j += 256){
            int k = hk[j];
            hmap[j] = (k < 0) ? 0xFFFFFFFFu : (((unsigned)k << 10) | (unsigned)hv[j]);
        }
        for (int i = t; i < NSLOT; i += 256){
            int v = s[i];
            unsigned idx = hsh(v);
            while (hk[idx] != v) idx = (idx+1)&(HB-1);
            rep[i] = hv[idx];
        }
        return;
    }
    const float* W = (m==0) ? Wp : (m==1) ? Wc : (m==2) ? Wl : Wr;
    unsigned short* WT = WT4 + (size_t)m*DIM*DIM;
    if (m < 2 && t < DIM){
        const float* avs = m ? ascv : aspv;
        const float* avd = m ? adcv : adpv;
        float* wab = wa + m*2*DIM;
        float sv = 0.f, dv = 0.f;
        for (int n = 0; n < DIM; n++){
            float w = W[t*DIM + n];
            sv += w*avs[n]; dv += w*avd[n];
        }
        wab[t] = sv; wab[DIM + t] = dv;
    }
    for (int j = t; j < DIM*DIM; j += blockDim.x){
        int n = j >> 7, k = j & 127;
        WT[n*DIM + k] = f2b(W[k*DIM + n]);
    }
}

// blocks [0,NCAST): cast (grid-stride, wave/node); [NCAST, NCAST+NBUILD): CSR build
__global__ __launch_bounds__(256) void k_castbuild(
        const float* __restrict__ X, const float* __restrict__ wa,
        unsigned* __restrict__ Xbf,
        float* __restrict__ asp, float* __restrict__ adp,
        float* __restrict__ asc, float* __restrict__ adc,
        const int* __restrict__ EI,
        const unsigned* __restrict__ bm, const unsigned* __restrict__ hmap,
        int* __restrict__ cnt, int* __restrict__ csr){
    __shared__ unsigned bms[NBM];
    __shared__ unsigned q[QCAP];
    __shared__ int qn;
    int bx = blockIdx.x;
    int lane = threadIdx.x & 63;
    int wib = threadIdx.x >> 6;
    if (bx < NCAST){
        for (int node = bx*4 + wib; node < NN; node += NCAST*4){
            float2 x = *(const float2*)&X[(size_t)node*DIM + lane*2];
            Xbf[(size_t)node*64 + lane] = (unsigned)f2b(x.x) | ((unsigned)f2b(x.y) << 16);
            float sp = x.x*wa[2*lane]     + x.y*wa[2*lane+1];
            float dp = x.x*wa[128+2*lane] + x.y*wa[128+2*lane+1];
            float sc = x.x*wa[256+2*lane] + x.y*wa[256+2*lane+1];
            float dc = x.x*wa[384+2*lane] + x.y*wa[384+2*lane+1];
            #pragma unroll
            for (int off = 32; off; off >>= 1){
                sp += __shfl_xor(sp, off); dp += __shfl_xor(dp, off);
                sc += __shfl_xor(sc, off); dc += __shfl_xor(dc, off);
            }
            if (lane == 0){ asp[node]=sp; adp[node]=dp; asc[node]=sc; adc[node]=dc; }
        }
        return;
    }
    int bb = bx - NCAST;
    int row = bb / 118, bxx = bb - row*118;
    for (int j = threadIdx.x; j < NBM; j += 256) bms[j] = bm[j];
    if (threadIdx.x == 0) qn = 0;
    __syncthreads();
    const int Q = NE/4;
    const int G = 118*256;
    const int4* dstp = (const int4*)(EI + (size_t)(2*row+1)*NE);
    const int4* srcp = (const int4*)(EI + (size_t)(2*row)*NE);
    int tid = bxx*256 + threadIdx.x;

    int4 d[4]; int ix[4]; bool va[4];
    #pragma unroll
    for (int u = 0; u < 4; u++){
        ix[u] = tid + u*G;
        va[u] = ix[u] < Q;
        d[u] = va[u] ? dstp[ix[u]] : make_int4(0,0,0,0);
    }
    unsigned mk[4];
    #pragma unroll
    for (int u = 0; u < 4; u++){
        unsigned m0 = va[u] ? ((bms[d[u].x>>5] >> (d[u].x&31)) & 1u) : 0u;
        unsigned m1 = va[u] ? ((bms[d[u].y>>5] >> (d[u].y&31)) & 1u) : 0u;
        unsigned m2 = va[u] ? ((bms[d[u].z>>5] >> (d[u].z&31)) & 1u) : 0u;
        unsigned m3 = va[u] ? ((bms[d[u].w>>5] >> (d[u].w&31)) & 1u) : 0u;
        mk[u] = m0 | (m1<<1) | (m2<<2) | (m3<<3);
    }
    int4 sv[4];
    #pragma unroll
    for (int u = 0; u < 4; u++)
        if (mk[u]) sv[u] = srcp[ix[u]];
    #pragma unroll
    for (int u = 0; u < 4; u++){
        #pragma unroll
        for (int c = 0; c < 4; c++){
            bool p = (mk[u] >> c) & 1u;
            unsigned long long bal = __ballot(p);
            if (bal){
                int cntw = __popcll(bal);
                int base = 0;
                if (lane == 0) base = atomicAdd(&qn, cntw);
                base = __shfl(base, 0);
                if (p){
                    int dv = (c==0)?d[u].x:(c==1)?d[u].y:(c==2)?d[u].z:d[u].w;
                    int so = (c==0)?sv[u].x:(c==1)?sv[u].y:(c==2)?sv[u].z:sv[u].w;
                    int pos = base + __popcll(bal & ((1ull<<lane)-1ull));
                    if (pos < QCAP) q[pos] = ((unsigned)dv<<15) | (unsigned)so;
                }
            }
        }
    }
    __syncthreads();
    int base = row*NSLOT;
    int tot = qn; if (tot > QCAP) tot = QCAP;
    for (int j = threadIdx.x; j < tot; j += 256){
        unsigned e = q[j];
        int dst = (int)(e >> 15);
        int src = (int)(e & 32767u);
        unsigned idx = hsh(dst);
        unsigned he;
        while (((he = hmap[idx]) >> 10) != (unsigned)dst) idx = (idx+1)&(HB-1);
        int sl = (int)(he & 1023u);
        int p = atomicAdd(&cnt[base+sl], 1);
        if (p < SEGCAP) csr[(size_t)(base+sl)*SEGCAP + p] = src;
    }
}

// blocks [0,NAGG): 16 segments/block -> aggregate to LDS -> 16x128x128 MFMA -> aggOut
// blocks [NAGG, NAGG+16): Xbf[s]@WrT -> xWr
__global__ __launch_bounds__(256) void k_aggemm(const unsigned* __restrict__ Xbf,
        const float* __restrict__ asp, const float* __restrict__ adp,
        const float* __restrict__ asc, const float* __restrict__ adc,
        const int* __restrict__ s, const int* __restrict__ cnt, const int* __restrict__ csr,
        const unsigned short* __restrict__ WT4,
        float* __restrict__ aggOut, float* __restrict__ xWr){
    __shared__ unsigned tile[16][72];   // 288B row: 16B-aligned, low-conflict
    int bx = blockIdx.x;
    int lane = threadIdx.x & 63;
    int wib = threadIdx.x >> 6;
    if (bx >= NAGG){
        int blk = bx - NAGG;
        const unsigned short* WT = WT4 + (size_t)3*DIM*DIM;
        int r0 = blk*64 + wib*16;
        int ar = r0 + (lane & 15); if (ar > NSLOT-1) ar = NSLOT-1;
        int g4 = lane >> 4;
        const unsigned short* Arow = (const unsigned short*)(Xbf + (size_t)s[ar]*64);
        bf16x8 Af[4];
        #pragma unroll
        for (int ks = 0; ks < 4; ks++)
            Af[ks] = *(const bf16x8*)&Arow[ks*32 + g4*8];
        int cl = lane & 15;
        #pragma unroll
        for (int ct = 0; ct < 8; ct++){
            f32x4 acc = {0.f,0.f,0.f,0.f};
            int bcol = ct*16 + cl;
            #pragma unroll
            for (int ks = 0; ks < 4; ks++){
                bf16x8 bF = *(const bf16x8*)&WT[bcol*DIM + ks*32 + g4*8];
                acc = __builtin_amdgcn_mfma_f32_16x16x32_bf16(Af[ks], bF, acc, 0, 0, 0);
            }
            #pragma unroll
            for (int r = 0; r < 4; r++){
                int rw = r0 + g4*4 + r;
                if (rw < NSLOT) xWr[(size_t)rw*DIM + bcol] = acc[r];
            }
        }
        return;
    }
    int base_gw = bx*16;
    int tg = base_gw >> 10;
    int g = tg % 3;
    const float* as = (g==1) ? asc : asp;
    const float* ad = (g==1) ? adc : adp;

    // ---- hoisted segment heads: all loads issued independently ----
    int nA[4], s0A[4], s1A[4];
    #pragma unroll
    for (int k = 0; k < 4; k++)
        nA[k] = cnt[base_gw + wib*4 + k];
    #pragma unroll
    for (int k = 0; k < 4; k++){
        const int* lst = csr + (size_t)(base_gw + wib*4 + k)*SEGCAP;
        s0A[k] = lst[lane];
        s1A[k] = (lane < 32) ? lst[64+lane] : 0;   // entries >=96 never used
    }
    #pragma unroll
    for (int k = 0; k < 4; k++){
        if (nA[k] > SEGCAP) nA[k] = SEGCAP;
        if (lane >= nA[k]) s0A[k] = 0;
        if (64+lane >= nA[k]) s1A[k] = 0;
    }
    float w0A[4], w1A[4], wsA[4], scA[4];
    unsigned pkvA[4];
    int vA[4];
    if (g < 2){
        #pragma unroll
        for (int k = 0; k < 4; k++)
            vA[k] = s[(base_gw + wib*4 + k) & (NSLOT-1)];
        float advA[4], easA[4];
        #pragma unroll
        for (int k = 0; k < 4; k++){ advA[k] = ad[vA[k]]; easA[k] = as[vA[k]]; }
        float e0A[4], e1A[4];
        #pragma unroll
        for (int k = 0; k < 4; k++){
            e0A[k] = as[s0A[k]];
            e1A[k] = as[s1A[k]];
        }
        #pragma unroll
        for (int k = 0; k < 4; k++)
            pkvA[k] = Xbf[(size_t)vA[k]*64 + lane];
        #pragma unroll
        for (int k = 0; k < 4; k++){
            float eself = lrelu(easA[k] + advA[k]);
            float e0 = (lane < nA[k])    ? lrelu(e0A[k] + advA[k]) : -3e38f;
            float e1 = (64+lane < nA[k]) ? lrelu(e1A[k] + advA[k]) : -3e38f;
            float m = fmaxf(eself, fmaxf(e0, e1));
            #pragma unroll
            for (int off = 32; off; off >>= 1) m = fmaxf(m, __shfl_xor(m, off));
            float w0 = (lane < nA[k])    ? __expf(e0 - m) : 0.f;
            float w1 = (64+lane < nA[k]) ? __expf(e1 - m) : 0.f;
            float ds = w0 + w1;
            #pragma unroll
            for (int off = 32; off; off >>= 1) ds += __shfl_xor(ds, off);
            float wself = __expf(eself - m);
            w0A[k] = w0; w1A[k] = w1; wsA[k] = wself;
            scA[k] = 1.f / (wself + ds);
        }
    } else {
        #pragma unroll
        for (int k = 0; k < 4; k++){
            w0A[k] = (lane < nA[k]) ? 1.f : 0.f;
            w1A[k] = (64+lane < nA[k]) ? 1.f : 0.f;
            wsA[k] = 0.f;
            scA[k] = 1.f / (float)(nA[k] > 0 ? nA[k] : 1);
        }
    }

    // ---- gather-accumulate per segment ----
    #pragma unroll
    for (int k = 0; k < 4; k++){
        int n = nA[k];
        int n0 = n < 64 ? n : 64;
        int src0 = s0A[k], src1 = s1A[k];
        float w0 = w0A[k], w1 = w1A[k];
        float a0 = 0.f, a1 = 0.f;
        int j = 0;
        for (; j+7 < n0; j += 8){
            int   si[8]; float qi[8]; unsigned ki[8];
            #pragma unroll
            for (int u = 0; u < 8; u++){ si[u] = __shfl(src0, j+u); qi[u] = __shfl(w0, j+u); }
            #pragma unroll
            for (int u = 0; u < 8; u++) ki[u] = Xbf[(size_t)si[u]*64 + lane];
            #pragma unroll
            for (int u = 0; u < 8; u++){ a0 += qi[u]*blo(ki[u]); a1 += qi[u]*bhi(ki[u]); }
        }
        for (; j+3 < n0; j += 4){
            int s0=__shfl(src0,j), s1=__shfl(src0,j+1), s2=__shfl(src0,j+2), s3=__shfl(src0,j+3);
            float q0=__shfl(w0,j), q1=__shfl(w0,j+1), q2=__shfl(w0,j+2), q3=__shfl(w0,j+3);
            unsigned k0=Xbf[(size_t)s0*64+lane];
            unsigned k1=Xbf[(size_t)s1*64+lane];
            unsigned k2=Xbf[(size_t)s2*64+lane];
            unsigned k3=Xbf[(size_t)s3*64+lane];
            a0 += q0*blo(k0) + q1*blo(k1) + q2*blo(k2) + q3*blo(k3);
            a1 += q0*bhi(k0) + q1*bhi(k1) + q2*bhi(k2) + q3*bhi(k3);
        }
        for (; j < n0; j++){
            int sj=__shfl(src0,j);
            float qj=__shfl(w0,j);
            unsigned pk=Xbf[(size_t)sj*64+lane];
            a0 += qj*blo(pk); a1 += qj*bhi(pk);
        }
        for (j = 64; j < n; j++){
            int sj=__shfl(src1,j-64);
            float qj=__shfl(w1,j-64);
            unsigned pk=Xbf[(size_t)sj*64+lane];
            a0 += qj*blo(pk); a1 += qj*bhi(pk);
        }
        if (g < 2){
            a0 += wsA[k]*blo(pkvA[k]);
            a1 += wsA[k]*bhi(pkvA[k]);
        }
        tile[wib*4+k][lane] = (unsigned)f2b(a0*scA[k]) | ((unsigned)f2b(a1*scA[k]) << 16);
    }
    __syncthreads();
    // GEMM: 16 rows x 128 cols, wave wib does cols [wib*32, wib*32+32)
    const unsigned short* WT = WT4 + (size_t)g*DIM*DIM;
    int r = lane & 15, g4 = lane >> 4;
    bf16x8 Af[4];
    #pragma unroll
    for (int ks = 0; ks < 4; ks++)
        Af[ks] = *(const bf16x8*)&tile[r][ks*16 + g4*4];
    #pragma unroll
    for (int ct = 0; ct < 2; ct++){
        f32x4 acc = {0.f,0.f,0.f,0.f};
        int bcol = wib*32 + ct*16 + r;
        #pragma unroll
        for (int ks = 0; ks < 4; ks++){
            bf16x8 bF = *(const bf16x8*)&WT[bcol*DIM + ks*32 + g4*8];
            acc = __builtin_amdgcn_mfma_f32_16x16x32_bf16(Af[ks], bF, acc, 0, 0, 0);
        }
        #pragma unroll
        for (int rr = 0; rr < 4; rr++){
            int segrow = g4*4 + rr;
            aggOut[(size_t)(base_gw + segrow)*DIM + bcol] = acc[rr];
        }
    }
}

__global__ void k_gather(const int* __restrict__ rep,
                         const float* __restrict__ aggOut, const float* __restrict__ xWr,
                         const float* __restrict__ bp, const float* __restrict__ bc,
                         const float* __restrict__ bl, const float* __restrict__ br,
                         float* __restrict__ out){
    int i = blockIdx.x*blockDim.x + threadIdx.x;
    if (i >= NT*NSLOT*DIM) return;
    int d = i & 127;
    int r = (i >> 7) & (NSLOT-1);
    int t = i >> 17;
    int rp = rep[r];
    size_t base = ((size_t)(t*3)*NSLOT + rp)*DIM + d;
    out[i] = (aggOut[base] + aggOut[base + NSLOT*DIM] + aggOut[base + 2*NSLOT*DIM]
              + xWr[(size_t)rp*DIM + d]
              + bp[d] + bc[d] + bl[d] + br[d]) * (1.f/3.f);
}

extern "C" void kernel_launch(void* const* d_in, const int* in_sizes, int n_in,
                              void* d_out, int out_size, void* d_ws, size_t ws_size,
                              hipStream_t stream) {
    const int*   s    = (const int*)d_in[0];
    const int*   EI   = (const int*)d_in[3];
    const float* X    = (const float*)d_in[4];
    const float* Wp   = (const float*)d_in[5];
    const float* aspv = (const float*)d_in[6];
    const float* adpv = (const float*)d_in[7];
    const float* bp   = (const float*)d_in[8];
    const float* Wc   = (const float*)d_in[9];
    const float* ascv = (const float*)d_in[10];
    const float* adcv = (const float*)d_in[11];
    const float* bc   = (const float*)d_in[12];
    const float* Wl   = (const float*)d_in[13];
    const float* bl   = (const float*)d_in[14];
    const float* Wr   = (const float*)d_in[15];
    const float* br   = (const float*)d_in[16];
    float* out = (float*)d_out;

    char* w = (char*)d_ws;
    unsigned* Xbf = (unsigned*)w; w += (size_t)NN*64*4;
    unsigned short* WT4 = (unsigned short*)w; w += (size_t)4*DIM*DIM*2;
    float* wa  = (float*)w; w += (size_t)4*DIM*4;
    float* asp = (float*)w; w += (size_t)NN*4;
    float* adp = (float*)w; w += (size_t)NN*4;
    float* asc = (float*)w; w += (size_t)NN*4;
    float* adc = (float*)w; w += (size_t)NN*4;
    unsigned* bm = (unsigned*)w; w += (size_t)((NBM+3)&~3)*4;
    unsigned* hmap = (unsigned*)w; w += (size_t)HB*4;
    int* rep  = (int*)w; w += (size_t)NSLOT*4;
    int* cnt  = (int*)w; w += (size_t)NSEG*4;
    int* csr  = (int*)w; w += (size_t)NSEG*SEGCAP*4;
    float* aggOut = (float*)w; w += (size_t)NSEG*DIM*4;
    float* xWr = (float*)w; w += (size_t)NSLOT*DIM*4;

    k_prep      <<<13, 256, 0, stream>>>(Wp, Wc, Wl, Wr, aspv, adpv, ascv, adcv,
                                         s, bm, hmap, rep, cnt, wa, WT4);
    k_castbuild <<<NCAST+NBUILD, 256, 0, stream>>>(X, wa, Xbf, asp, adp, asc, adc,
                                                   EI, bm, hmap, cnt, csr);
    k_aggemm    <<<NAGG+16, 256, 0, stream>>>(Xbf, asp, adp, asc, adc, s, cnt, csr,
                                              WT4, aggOut, xWr);
    k_gather    <<<NT*NSLOT*DIM/256, 256, 0, stream>>>(rep, aggOut, xWr, bp, bc, bl, br, out);
}